// Round 3
// baseline (87.508 us; speedup 1.0000x reference)
//
#include <hip/hip_runtime.h>

#define L_SEQ 4096
#define E_DIM 512
#define B_DIM 4

// ---------------------------------------------------------------------------
// Kernel 1: per-vocab score  sv[v] = dot(emb[v,:], score_w)   (V=256 rows)
// ---------------------------------------------------------------------------
__global__ void k_vocab_score(const float* __restrict__ emb,
                              const float* __restrict__ w,
                              float* __restrict__ sv) {
    int v = blockIdx.x;
    int lane = threadIdx.x;  // block = 64 threads = 1 wave
    float acc = 0.f;
#pragma unroll
    for (int e = lane; e < E_DIM; e += 64) acc += emb[v * E_DIM + e] * w[e];
#pragma unroll
    for (int off = 32; off > 0; off >>= 1) acc += __shfl_down(acc, off);
    if (lane == 0) sv[v] = acc;
}

// ---------------------------------------------------------------------------
// Kernel 2: per-token score  t[i] = sv[seq[i]]
// ---------------------------------------------------------------------------
__global__ void k_token_score(const int* __restrict__ seq,
                              const float* __restrict__ sv,
                              float* __restrict__ t, int n) {
    int i = blockIdx.x * blockDim.x + threadIdx.x;
    if (i < n) t[i] = sv[seq[i]];
}

// ---------------------------------------------------------------------------
// Kernel 3: main. One wave (64 lanes) per output row (b,l).
// rep_k for block-size bs is the mean embedding of the PREVIOUS block
// (positions p with p/bs == l/bs - 1), zero-vector for the first block.
// score_b cancels in softmax; zero-rep score contribution is 0.
// out[b,l,:] = w0*emb[seq[l]] + sum_k (w_k/bs_k) * sum_{p in prevblk_k} emb[seq[p]]
// ---------------------------------------------------------------------------
__global__ __launch_bounds__(256) void k_main(const int* __restrict__ seq,
                                              const float* __restrict__ emb,
                                              const float* __restrict__ t,
                                              float* __restrict__ out) {
    int wid = threadIdx.x >> 6;
    int lane = threadIdx.x & 63;
    int row = blockIdx.x * 4 + wid;          // B*L = 16384 rows total
    int b = row >> 12;                       // row / 4096
    int l = row & (L_SEQ - 1);
    const float* tb = t + b * L_SEQ;
    const int* seqb = seq + b * L_SEQ;

    // ---- scalar phase (redundant across lanes; wave-uniform) ----
    float sc0 = tb[l];
    int j2 = (l >> 1) - 1, j3 = l / 3 - 1, j4 = (l >> 2) - 1;
    int s2 = j2 * 2, s3 = j3 * 3, s4 = j4 * 4;  // prev-block starts (negative if none)
    float sc1 = 0.f, sc2 = 0.f, sc3 = 0.f;
    if (j2 >= 0) sc1 = 0.5f * (tb[s2] + tb[s2 + 1]);
    if (j3 >= 0) sc2 = (1.f / 3.f) * (tb[s3] + tb[s3 + 1] + tb[s3 + 2]);
    if (j4 >= 0) sc3 = 0.25f * (tb[s4] + tb[s4 + 1] + tb[s4 + 2] + tb[s4 + 3]);

    float m = fmaxf(fmaxf(sc0, sc1), fmaxf(sc2, sc3));
    float w0 = __expf(sc0 - m), w1 = __expf(sc1 - m);
    float w2 = __expf(sc2 - m), w3 = __expf(sc3 - m);
    float inv = 1.f / (w0 + w1 + w2 + w3);
    w0 *= inv;                  // coefficient of current token
    w1 *= inv * 0.5f;           // per-member coefficient of prev bs=2 block
    w2 *= inv * (1.f / 3.f);    // per-member coefficient of prev bs=3 block
    w3 *= inv * 0.25f;          // per-member coefficient of prev bs=4 block

    // gather window [lo, l]; width <= 8. Invalid (negative) starts clamp to 0;
    // their positions get coefficient 0 and are skipped.
    int lo = min(min(s2, s3), min(s4, l));
    lo = max(lo, 0);

    float4 acc0 = {0.f, 0.f, 0.f, 0.f};
    float4 acc1 = {0.f, 0.f, 0.f, 0.f};
#pragma unroll
    for (int i = 0; i < 8; ++i) {
        int p = lo + i;
        if (p > l) break;
        // membership tests: if jk < 0 then s_k = -bs_k and p - s_k >= bs_k -> false
        float cc = (p == l) ? w0 : 0.f;
        if ((unsigned)(p - s2) < 2u) cc += w1;
        if ((unsigned)(p - s3) < 3u) cc += w2;
        if ((unsigned)(p - s4) < 4u) cc += w3;
        if (cc == 0.f) continue;             // gap position (e.g. l-1 sometimes)
        int v = seqb[p];                     // wave-uniform
        const float4* er = (const float4*)(emb + v * E_DIM);
        float4 e0 = er[lane];                // 2 KB row: L1/L2 resident
        float4 e1 = er[lane + 64];
        acc0.x += cc * e0.x; acc0.y += cc * e0.y;
        acc0.z += cc * e0.z; acc0.w += cc * e0.w;
        acc1.x += cc * e1.x; acc1.y += cc * e1.y;
        acc1.z += cc * e1.z; acc1.w += cc * e1.w;
    }

    float4* orow = (float4*)(out + (size_t)row * E_DIM);
    orow[lane] = acc0;
    orow[lane + 64] = acc1;
}

// ---------------------------------------------------------------------------
extern "C" void kernel_launch(void* const* d_in, const int* in_sizes, int n_in,
                              void* d_out, int out_size, void* d_ws, size_t ws_size,
                              hipStream_t stream) {
    const int* seq = (const int*)d_in[0];        // (B, L) int32
    // d_in[1] = group_id: deterministic (pos//bs + 1), recomputed analytically
    const float* emb = (const float*)d_in[2];    // (V, E) f32
    const float* sw = (const float*)d_in[3];     // (E,) f32
    // d_in[4] = score_b: cancels in softmax, unused
    float* out = (float*)d_out;                  // (B, L, E) f32

    float* sv = (float*)d_ws;                    // 256 floats
    float* t = sv + 256;                         // B*L floats

    const int n = B_DIM * L_SEQ;                 // 16384

    k_vocab_score<<<256, 64, 0, stream>>>(emb, sw, sv);
    k_token_score<<<(n + 255) / 256, 256, 0, stream>>>(seq, sv, t, n);
    k_main<<<n / 4, 256, 0, stream>>>(seq, emb, t, out);
}

// Round 5
// 82.846 us; speedup vs baseline: 1.0563x; 1.0563x over previous
//
#include <hip/hip_runtime.h>

#define L_SEQ 4096
#define E_DIM 512
#define B_DIM 4

typedef float f32x4 __attribute__((ext_vector_type(4)));  // native vec for nontemporal store

// ---------------------------------------------------------------------------
// Single fused kernel. One wave (64 lanes) per output row (b,l).
//
// Math (verified passing in round 3):
//   rep_k (block-size bs_k in {2,3,4}) = mean emb of the PREVIOUS block
//   (positions p with p/bs == l/bs - 1); zero-vector for the first block
//   (its score contribution is dot(0,w)=0). score_b cancels in softmax.
//   out[b,l,:] = c0*emb[seq[l]] + sum_k c_k/bs_k * sum_{p in prevblk_k} emb[seq[p]]
//
// Fusion: every score needs t[p] = dot(emb[seq[p]], score_w) only for p in
// the gather window [lo, l] (width <= 8), whose emb rows we load into
// registers anyway. Compute per-lane partial dots, butterfly-reduce the four
// score accumulators (24 shfl), softmax, then reuse the SAME registers for
// the weighted accumulation. One launch, no workspace, no t round-trip.
// ---------------------------------------------------------------------------
__global__ __launch_bounds__(256) void k_fused(const int* __restrict__ seq,
                                               const float* __restrict__ emb,
                                               const float* __restrict__ w,
                                               float* __restrict__ out) {
    int wid = threadIdx.x >> 6;
    int lane = threadIdx.x & 63;
    int row = blockIdx.x * 4 + wid;          // B*L = 16384 rows
    int b = row >> 12;                       // row / 4096
    int l = row & (L_SEQ - 1);
    const int* seqb = seq + b * L_SEQ;

    // prev-block starts (negative if this is the first block of that size)
    int j2 = (l >> 1) - 1, j3 = l / 3 - 1, j4 = (l >> 2) - 1;
    int s2 = j2 * 2, s3 = j3 * 3, s4 = j4 * 4;
    int lo = max(min(min(s2, s3), min(s4, l)), 0);   // window [lo, l], width <= 8

    // score_w fragment: lane owns 8 of 512 elements
    const f32x4* w4 = (const f32x4*)w;
    f32x4 wv0 = w4[lane];
    f32x4 wv1 = w4[lane + 64];

    // ---- load all (<=8) emb rows of the window into registers ----
    f32x4 e0[8], e1[8];
#pragma unroll
    for (int i = 0; i < 8; ++i) {
        int p = lo + i;
        int v = seqb[min(p, l)];             // clamp: p>l rows get coeff 0 anyway
        const f32x4* er = (const f32x4*)(emb + v * E_DIM);
        e0[i] = er[lane];
        e1[i] = er[lane + 64];
    }

    // ---- per-lane partial score accumulators ----
    // Membership tests: for p>l, p-s_k >= bs_k always (since s_k+bs_k-1 <= l),
    // and for first-blocks s_k = -bs_k so p-s_k >= bs_k for all p >= 0.
    float t0 = 0.f, t1 = 0.f, t2 = 0.f, t3 = 0.f;
#pragma unroll
    for (int i = 0; i < 8; ++i) {
        int p = lo + i;
        f32x4 d4 = e0[i] * wv0 + e1[i] * wv1;
        float d = d4.x + d4.y + d4.z + d4.w;
        if (p == l) t0 += d;
        if ((unsigned)(p - s2) < 2u) t1 += d;
        if ((unsigned)(p - s3) < 3u) t2 += d;
        if ((unsigned)(p - s4) < 4u) t3 += d;
    }
    // butterfly reduce across the wave (result broadcast to all lanes)
#pragma unroll
    for (int off = 32; off > 0; off >>= 1) {
        t0 += __shfl_xor(t0, off);
        t1 += __shfl_xor(t1, off);
        t2 += __shfl_xor(t2, off);
        t3 += __shfl_xor(t3, off);
    }
    float sc0 = t0;                  // current-token score
    float sc1 = t1 * 0.5f;           // mean over prev bs=2 block (0 if empty)
    float sc2 = t2 * (1.f / 3.f);
    float sc3 = t3 * 0.25f;

    // ---- softmax over the 4 scores (score_b cancels; mask provably false) ----
    float m = fmaxf(fmaxf(sc0, sc1), fmaxf(sc2, sc3));
    float q0 = __expf(sc0 - m), q1 = __expf(sc1 - m);
    float q2 = __expf(sc2 - m), q3 = __expf(sc3 - m);
    float inv = 1.f / (q0 + q1 + q2 + q3);
    float c0 = q0 * inv;             // coefficient of current token
    float c1 = q1 * inv * 0.5f;      // per-member coefficient, prev bs=2 block
    float c2 = q2 * inv * (1.f / 3.f);
    float c3 = q3 * inv * 0.25f;

    // ---- weighted accumulation, reusing the in-register rows ----
    f32x4 a0 = {0.f, 0.f, 0.f, 0.f};
    f32x4 a1 = {0.f, 0.f, 0.f, 0.f};
#pragma unroll
    for (int i = 0; i < 8; ++i) {
        int p = lo + i;
        float cc = (p == l) ? c0 : 0.f;
        if ((unsigned)(p - s2) < 2u) cc += c1;
        if ((unsigned)(p - s3) < 3u) cc += c2;
        if ((unsigned)(p - s4) < 4u) cc += c3;
        a0 += cc * e0[i];
        a1 += cc * e1[i];
    }

    f32x4* orow = (f32x4*)(out + (size_t)row * E_DIM);
    __builtin_nontemporal_store(a0, &orow[lane]);        // write-once output:
    __builtin_nontemporal_store(a1, &orow[lane + 64]);   // don't pollute L2
}

// ---------------------------------------------------------------------------
extern "C" void kernel_launch(void* const* d_in, const int* in_sizes, int n_in,
                              void* d_out, int out_size, void* d_ws, size_t ws_size,
                              hipStream_t stream) {
    const int* seq = (const int*)d_in[0];        // (B, L) int32
    // d_in[1] = group_id: deterministic (pos//bs + 1), recomputed analytically
    const float* emb = (const float*)d_in[2];    // (V, E) f32
    const float* sw = (const float*)d_in[3];     // (E,) f32
    // d_in[4] = score_b: cancels in softmax, unused
    float* out = (float*)d_out;                  // (B, L, E) f32

    const int n = B_DIM * L_SEQ;                 // 16384 rows, 4 waves/block
    k_fused<<<n / 4, 256, 0, stream>>>(seq, emb, sw, out);
}

// Round 11
// 77.489 us; speedup vs baseline: 1.1293x; 1.0691x over previous
//
#include <hip/hip_runtime.h>

#define L_SEQ 4096
#define E_DIM 512
#define B_DIM 4

typedef float f32x4 __attribute__((ext_vector_type(4)));

// ---------------------------------------------------------------------------
// Fused kernel, TWO consecutive output rows per wave.
//
// Math (verified passing R3/R5):
//   rep_k (bs_k in {2,3,4}) = mean emb of the PREVIOUS block of l; zero for
//   the first block (score contribution 0). score_b cancels in softmax.
//   out[b,l,:] = c0*emb[seq[l]] + sum_k c_k/bs_k * sum_{p in prevblk_k} emb[seq[p]]
//
// Window math (verified mod-12 exhaustive): for rows {l0=2r, l1=2r+1} the
// union gather window is [l0-6, l0+1] — exactly 8 positions. The same 8
// in-register emb rows serve both outputs: half the waves, half the gather
// traffic vs one-row-per-wave.
//
// p>l positions: all membership tests fail (s_k+bs_k-1 <= l). p<0 positions
// (only when l0<6): tests CAN spuriously pass for first-blocks (s_k=-bs_k),
// so the loaded rows are zeroed via `keep` — their contribution to scores
// and output is then exactly 0, matching the reference's zero-rep. (R7 bug.)
// ---------------------------------------------------------------------------
__global__ __launch_bounds__(256) void k_fused2(const int* __restrict__ seq,
                                                const float* __restrict__ emb,
                                                const float* __restrict__ w,
                                                float* __restrict__ out) {
    int wid = threadIdx.x >> 6;
    int lane = threadIdx.x & 63;
    int q = blockIdx.x * 4 + wid;            // row-pair index, 8192 total
    int b = q >> 11;                         // 2048 pairs per batch row
    int l0 = (q & 2047) * 2;                 // even row
    int l1 = l0 + 1;                         // odd row
    const int* seqb = seq + b * L_SEQ;

    // prev-block starts for both rows (negative if first block)
    int s2a = ((l0 >> 1) - 1) * 2, s3a = (l0 / 3 - 1) * 3, s4a = ((l0 >> 2) - 1) * 4;
    int s2b = ((l1 >> 1) - 1) * 2, s3b = (l1 / 3 - 1) * 3, s4b = ((l1 >> 2) - 1) * 4;
    int W = l0 - 6;                          // window [W, W+7] = [l0-6, l1]

    // score_w fragment: lane owns 8 of 512 elements
    const f32x4* w4 = (const f32x4*)w;
    f32x4 wv0 = w4[lane];
    f32x4 wv1 = w4[lane + 64];

    // ---- load the 8 shared emb rows into registers (zeroed for p<0) ----
    f32x4 e0[8], e1[8];
#pragma unroll
    for (int i = 0; i < 8; ++i) {
        int p = W + i;
        int v = seqb[max(p, 0)];
        const f32x4* er = (const f32x4*)(emb + v * E_DIM);
        float keep = (p >= 0) ? 1.f : 0.f;   // kill p<0 rows entirely (R7 fix)
        e0[i] = er[lane] * keep;
        e1[i] = er[lane + 64] * keep;
    }

    // ---- per-lane partial score accumulators for both rows ----
    float tA0 = 0.f, tA1 = 0.f, tA2 = 0.f, tA3 = 0.f;
    float tB0 = 0.f, tB1 = 0.f, tB2 = 0.f, tB3 = 0.f;
#pragma unroll
    for (int i = 0; i < 8; ++i) {
        int p = W + i;
        f32x4 d4 = e0[i] * wv0 + e1[i] * wv1;
        float d = d4.x + d4.y + d4.z + d4.w;  // 0 for p<0 rows
        if (p == l0) tA0 += d;
        if ((unsigned)(p - s2a) < 2u) tA1 += d;
        if ((unsigned)(p - s3a) < 3u) tA2 += d;
        if ((unsigned)(p - s4a) < 4u) tA3 += d;
        if (p == l1) tB0 += d;
        if ((unsigned)(p - s2b) < 2u) tB1 += d;
        if ((unsigned)(p - s3b) < 3u) tB2 += d;
        if ((unsigned)(p - s4b) < 4u) tB3 += d;
    }
    // butterfly reduce (broadcast result to all lanes)
#pragma unroll
    for (int off = 32; off > 0; off >>= 1) {
        tA0 += __shfl_xor(tA0, off); tA1 += __shfl_xor(tA1, off);
        tA2 += __shfl_xor(tA2, off); tA3 += __shfl_xor(tA3, off);
        tB0 += __shfl_xor(tB0, off); tB1 += __shfl_xor(tB1, off);
        tB2 += __shfl_xor(tB2, off); tB3 += __shfl_xor(tB3, off);
    }

    // ---- softmax over 4 scores, per row ----
    float scA1 = tA1 * 0.5f, scA2 = tA2 * (1.f / 3.f), scA3 = tA3 * 0.25f;
    float mA = fmaxf(fmaxf(tA0, scA1), fmaxf(scA2, scA3));
    float qA0 = __expf(tA0 - mA), qA1 = __expf(scA1 - mA);
    float qA2 = __expf(scA2 - mA), qA3 = __expf(scA3 - mA);
    float invA = 1.f / (qA0 + qA1 + qA2 + qA3);
    float cA0 = qA0 * invA, cA1 = qA1 * invA * 0.5f;
    float cA2 = qA2 * invA * (1.f / 3.f), cA3 = qA3 * invA * 0.25f;

    float scB1 = tB1 * 0.5f, scB2 = tB2 * (1.f / 3.f), scB3 = tB3 * 0.25f;
    float mB = fmaxf(fmaxf(tB0, scB1), fmaxf(scB2, scB3));
    float qB0 = __expf(tB0 - mB), qB1 = __expf(scB1 - mB);
    float qB2 = __expf(scB2 - mB), qB3 = __expf(scB3 - mB);
    float invB = 1.f / (qB0 + qB1 + qB2 + qB3);
    float cB0 = qB0 * invB, cB1 = qB1 * invB * 0.5f;
    float cB2 = qB2 * invB * (1.f / 3.f), cB3 = qB3 * invB * 0.25f;

    // ---- weighted accumulation for both rows from the shared registers ----
    // (p<0 rows are zero vectors, so spurious memberships contribute 0.)
    f32x4 aA0 = {0.f, 0.f, 0.f, 0.f}, aA1 = {0.f, 0.f, 0.f, 0.f};
    f32x4 aB0 = {0.f, 0.f, 0.f, 0.f}, aB1 = {0.f, 0.f, 0.f, 0.f};
#pragma unroll
    for (int i = 0; i < 8; ++i) {
        int p = W + i;
        float ca = (p == l0) ? cA0 : 0.f;
        if ((unsigned)(p - s2a) < 2u) ca += cA1;
        if ((unsigned)(p - s3a) < 3u) ca += cA2;
        if ((unsigned)(p - s4a) < 4u) ca += cA3;
        float cb = (p == l1) ? cB0 : 0.f;
        if ((unsigned)(p - s2b) < 2u) cb += cB1;
        if ((unsigned)(p - s3b) < 3u) cb += cB2;
        if ((unsigned)(p - s4b) < 4u) cb += cB3;
        aA0 += ca * e0[i]; aA1 += ca * e1[i];
        aB0 += cb * e0[i]; aB1 += cb * e1[i];
    }

    size_t base = (size_t)(b * L_SEQ + l0) * E_DIM;
    f32x4* rowA = (f32x4*)(out + base);
    f32x4* rowB = (f32x4*)(out + base + E_DIM);
    __builtin_nontemporal_store(aA0, &rowA[lane]);
    __builtin_nontemporal_store(aA1, &rowA[lane + 64]);
    __builtin_nontemporal_store(aB0, &rowB[lane]);
    __builtin_nontemporal_store(aB1, &rowB[lane + 64]);
}

// ---------------------------------------------------------------------------
extern "C" void kernel_launch(void* const* d_in, const int* in_sizes, int n_in,
                              void* d_out, int out_size, void* d_ws, size_t ws_size,
                              hipStream_t stream) {
    const int* seq = (const int*)d_in[0];        // (B, L) int32
    // d_in[1] = group_id: deterministic (pos//bs + 1), recomputed analytically
    const float* emb = (const float*)d_in[2];    // (V, E) f32
    const float* sw = (const float*)d_in[3];     // (E,) f32
    // d_in[4] = score_b: cancels in softmax, unused
    float* out = (float*)d_out;                  // (B, L, E) f32

    const int npairs = B_DIM * L_SEQ / 2;        // 8192 row-pairs, 4 per block
    k_fused2<<<npairs / 4, 256, 0, stream>>>(seq, emb, sw, out);
}

// Round 12
// 76.564 us; speedup vs baseline: 1.1429x; 1.0121x over previous
//
#include <hip/hip_runtime.h>

#define L_SEQ 4096
#define E_DIM 512
#define B_DIM 4

typedef float f32x4 __attribute__((ext_vector_type(4)));

// ---------------------------------------------------------------------------
// Fused kernel, FOUR consecutive output rows per wave (l0 = 4r).
//
// Math (verified passing R3/R5/R11):
//   rep_k (bs_k in {2,3,4}) = mean emb of the PREVIOUS block of l; zero for
//   the first block (score contribution 0). score_b cancels in softmax.
//   out[b,l,:] = c0*emb[seq[l]] + sum_k c_k/bs_k * sum_{p in prevblk_k} emb[seq[p]]
//
// Window math for rows {l0..l0+3}, l0 % 4 == 0:
//   s4 = l0-4 for all rows; s2 in {l0-2 (rows A,B), l0 (rows C,D)};
//   s3 = l-(l mod 3)-3 >= l0-5; max position = l0+3.
//   Union window = [l0-5, l0+3] — exactly 9 positions. 2.25 loads/output
//   vs the pair kernel's 4.
//
// p>l positions: all membership tests fail (s_k+bs_k-1 <= l, re-derived for
// all 4 rows). p<0 positions (only l0 in {0,4}): tests can spuriously pass
// for first-blocks (s_k=-bs_k), so loaded rows are zeroed via `keep` —
// contribution is exactly 0, matching the reference's zero-rep (R7 fix).
// ---------------------------------------------------------------------------
__global__ __launch_bounds__(256) void k_fused4(const int* __restrict__ seq,
                                                const float* __restrict__ emb,
                                                const float* __restrict__ w,
                                                float* __restrict__ out) {
    int wid = threadIdx.x >> 6;
    int lane = threadIdx.x & 63;
    int q = blockIdx.x * 4 + wid;            // 4-row group index, 4096 total
    int b = q >> 10;                         // 1024 groups per batch row
    int l0 = (q & 1023) * 4;
    const int* seqb = seq + b * L_SEQ;

    int lA = l0, lB = l0 + 1, lC = l0 + 2, lD = l0 + 3;
    // prev-block starts per row (negative if first block)
    int s2A = ((lA >> 1) - 1) * 2, s3A = (lA / 3 - 1) * 3, s4A = ((lA >> 2) - 1) * 4;
    int s2B = ((lB >> 1) - 1) * 2, s3B = (lB / 3 - 1) * 3, s4B = ((lB >> 2) - 1) * 4;
    int s2C = ((lC >> 1) - 1) * 2, s3C = (lC / 3 - 1) * 3, s4C = ((lC >> 2) - 1) * 4;
    int s2D = ((lD >> 1) - 1) * 2, s3D = (lD / 3 - 1) * 3, s4D = ((lD >> 2) - 1) * 4;
    int W = l0 - 5;                          // window [W, W+8] = [l0-5, l0+3]

    // score_w fragment: lane owns 8 of 512 elements
    const f32x4* w4 = (const f32x4*)w;
    f32x4 wv0 = w4[lane];
    f32x4 wv1 = w4[lane + 64];

    // ---- load the 9 shared emb rows into registers (zeroed for p<0) ----
    f32x4 e0[9], e1[9];
#pragma unroll
    for (int i = 0; i < 9; ++i) {
        int p = W + i;
        int v = seqb[max(p, 0)];
        const f32x4* er = (const f32x4*)(emb + v * E_DIM);
        float keep = (p >= 0) ? 1.f : 0.f;   // kill p<0 rows entirely
        e0[i] = er[lane] * keep;
        e1[i] = er[lane + 64] * keep;
    }

    // ---- per-lane partial score accumulators, 4 per row ----
    float tA0 = 0.f, tA1 = 0.f, tA2 = 0.f, tA3 = 0.f;
    float tB0 = 0.f, tB1 = 0.f, tB2 = 0.f, tB3 = 0.f;
    float tC0 = 0.f, tC1 = 0.f, tC2 = 0.f, tC3 = 0.f;
    float tD0 = 0.f, tD1 = 0.f, tD2 = 0.f, tD3 = 0.f;
#pragma unroll
    for (int i = 0; i < 9; ++i) {
        int p = W + i;
        f32x4 d4 = e0[i] * wv0 + e1[i] * wv1;
        float d = d4.x + d4.y + d4.z + d4.w;  // 0 for p<0 rows
        if (p == lA) tA0 += d;
        if ((unsigned)(p - s2A) < 2u) tA1 += d;
        if ((unsigned)(p - s3A) < 3u) tA2 += d;
        if ((unsigned)(p - s4A) < 4u) tA3 += d;
        if (p == lB) tB0 += d;
        if ((unsigned)(p - s2B) < 2u) tB1 += d;
        if ((unsigned)(p - s3B) < 3u) tB2 += d;
        if ((unsigned)(p - s4B) < 4u) tB3 += d;
        if (p == lC) tC0 += d;
        if ((unsigned)(p - s2C) < 2u) tC1 += d;
        if ((unsigned)(p - s3C) < 3u) tC2 += d;
        if ((unsigned)(p - s4C) < 4u) tC3 += d;
        if (p == lD) tD0 += d;
        if ((unsigned)(p - s2D) < 2u) tD1 += d;
        if ((unsigned)(p - s3D) < 3u) tD2 += d;
        if ((unsigned)(p - s4D) < 4u) tD3 += d;
    }
    // butterfly reduce (broadcast to all lanes)
#pragma unroll
    for (int off = 32; off > 0; off >>= 1) {
        tA0 += __shfl_xor(tA0, off); tA1 += __shfl_xor(tA1, off);
        tA2 += __shfl_xor(tA2, off); tA3 += __shfl_xor(tA3, off);
        tB0 += __shfl_xor(tB0, off); tB1 += __shfl_xor(tB1, off);
        tB2 += __shfl_xor(tB2, off); tB3 += __shfl_xor(tB3, off);
        tC0 += __shfl_xor(tC0, off); tC1 += __shfl_xor(tC1, off);
        tC2 += __shfl_xor(tC2, off); tC3 += __shfl_xor(tC3, off);
        tD0 += __shfl_xor(tD0, off); tD1 += __shfl_xor(tD1, off);
        tD2 += __shfl_xor(tD2, off); tD3 += __shfl_xor(tD3, off);
    }

    // ---- softmax over 4 scores, per row (score_b cancels; mask all-false) ----
#define SOFTMAX4(t0, t1, t2, t3, c0, c1, c2, c3)                               \
    {                                                                          \
        float s1 = (t1) * 0.5f, s2 = (t2) * (1.f / 3.f), s3 = (t3) * 0.25f;    \
        float m = fmaxf(fmaxf((t0), s1), fmaxf(s2, s3));                       \
        float e0_ = __expf((t0) - m), e1_ = __expf(s1 - m);                    \
        float e2_ = __expf(s2 - m), e3_ = __expf(s3 - m);                      \
        float inv = 1.f / (e0_ + e1_ + e2_ + e3_);                             \
        c0 = e0_ * inv; c1 = e1_ * inv * 0.5f;                                 \
        c2 = e2_ * inv * (1.f / 3.f); c3 = e3_ * inv * 0.25f;                  \
    }
    float cA0, cA1, cA2, cA3; SOFTMAX4(tA0, tA1, tA2, tA3, cA0, cA1, cA2, cA3);
    float cB0, cB1, cB2, cB3; SOFTMAX4(tB0, tB1, tB2, tB3, cB0, cB1, cB2, cB3);
    float cC0, cC1, cC2, cC3; SOFTMAX4(tC0, tC1, tC2, tC3, cC0, cC1, cC2, cC3);
    float cD0, cD1, cD2, cD3; SOFTMAX4(tD0, tD1, tD2, tD3, cD0, cD1, cD2, cD3);
#undef SOFTMAX4

    // ---- weighted accumulation for 4 rows from the shared registers ----
    f32x4 aA0 = {0,0,0,0}, aA1 = {0,0,0,0}, aB0 = {0,0,0,0}, aB1 = {0,0,0,0};
    f32x4 aC0 = {0,0,0,0}, aC1 = {0,0,0,0}, aD0 = {0,0,0,0}, aD1 = {0,0,0,0};
#pragma unroll
    for (int i = 0; i < 9; ++i) {
        int p = W + i;
        float ca = (p == lA) ? cA0 : 0.f;
        if ((unsigned)(p - s2A) < 2u) ca += cA1;
        if ((unsigned)(p - s3A) < 3u) ca += cA2;
        if ((unsigned)(p - s4A) < 4u) ca += cA3;
        float cb = (p == lB) ? cB0 : 0.f;
        if ((unsigned)(p - s2B) < 2u) cb += cB1;
        if ((unsigned)(p - s3B) < 3u) cb += cB2;
        if ((unsigned)(p - s4B) < 4u) cb += cB3;
        float cc = (p == lC) ? cC0 : 0.f;
        if ((unsigned)(p - s2C) < 2u) cc += cC1;
        if ((unsigned)(p - s3C) < 3u) cc += cC2;
        if ((unsigned)(p - s4C) < 4u) cc += cC3;
        float cd = (p == lD) ? cD0 : 0.f;
        if ((unsigned)(p - s2D) < 2u) cd += cD1;
        if ((unsigned)(p - s3D) < 3u) cd += cD2;
        if ((unsigned)(p - s4D) < 4u) cd += cD3;
        aA0 += ca * e0[i]; aA1 += ca * e1[i];
        aB0 += cb * e0[i]; aB1 += cb * e1[i];
        aC0 += cc * e0[i]; aC1 += cc * e1[i];
        aD0 += cd * e0[i]; aD1 += cd * e1[i];
    }

    size_t base = (size_t)(b * L_SEQ + l0) * E_DIM;
    f32x4* rA = (f32x4*)(out + base);
    f32x4* rB = (f32x4*)(out + base + E_DIM);
    f32x4* rC = (f32x4*)(out + base + 2 * E_DIM);
    f32x4* rD = (f32x4*)(out + base + 3 * E_DIM);
    __builtin_nontemporal_store(aA0, &rA[lane]);
    __builtin_nontemporal_store(aA1, &rA[lane + 64]);
    __builtin_nontemporal_store(aB0, &rB[lane]);
    __builtin_nontemporal_store(aB1, &rB[lane + 64]);
    __builtin_nontemporal_store(aC0, &rC[lane]);
    __builtin_nontemporal_store(aC1, &rC[lane + 64]);
    __builtin_nontemporal_store(aD0, &rD[lane]);
    __builtin_nontemporal_store(aD1, &rD[lane + 64]);
}

// ---------------------------------------------------------------------------
extern "C" void kernel_launch(void* const* d_in, const int* in_sizes, int n_in,
                              void* d_out, int out_size, void* d_ws, size_t ws_size,
                              hipStream_t stream) {
    const int* seq = (const int*)d_in[0];        // (B, L) int32
    // d_in[1] = group_id: deterministic (pos//bs + 1), recomputed analytically
    const float* emb = (const float*)d_in[2];    // (V, E) f32
    const float* sw = (const float*)d_in[3];     // (E,) f32
    // d_in[4] = score_b: cancels in softmax, unused
    float* out = (float*)d_out;                  // (B, L, E) f32

    const int ngroups = B_DIM * L_SEQ / 4;       // 4096 groups, 4 waves/block
    k_fused4<<<ngroups / 4, 256, 0, stream>>>(seq, emb, sw, out);
}